// Round 1
// baseline (1070.752 us; speedup 1.0000x reference)
//
#include <hip/hip_runtime.h>
#include <math.h>

#define BLK 256
#define TILE 32
#define HALO 5
#define RR 42            // TILE + 2*HALO
#define SPITCH 44        // input tile row pitch (dwords): %4==0 (b128 align), %32=12 (bank rotate)
#define HPITCH 36        // h-array row pitch: %4==0, %32=4
#define IMG_W 512
#define IMG_H 512
#define INV_NPIX (1.0 / 25165824.0)   // 32*3*512*512

__global__ void ssim_zero_acc(double* acc) {
    int i = threadIdx.x;
    if (i < 3) acc[i] = 0.0;
}

__global__ __launch_bounds__(BLK, 3) void ssim_tile_kernel(
    const float* __restrict__ img1, const float* __restrict__ img2,
    const float* __restrict__ win, double* __restrict__ acc)
{
    __shared__ float s1[RR][SPITCH];
    __shared__ float s2[RR][SPITCH];
    __shared__ float hq[5][RR][HPITCH];   // 0:mu1 1:mu2 2:x11 3:x22 4:x12 (h-pass)
    __shared__ float gw[16];
    __shared__ float red[3][4];

    const int tid = threadIdx.x;
    // Recover the separable 1-D Gaussian from the 2-D window's diagonal:
    // w2d[i][i] = g[i]^2  (channel 0 of the (3,1,11,11) window)
    if (tid < 11) gw[tid] = sqrtf(win[tid * 12]);

    const int plane = blockIdx.z;                 // 0..95 (N*C planes)
    const int base  = plane * (IMG_W * IMG_H);
    const int x0 = blockIdx.x * TILE - HALO;
    const int y0 = blockIdx.y * TILE - HALO;

    // ---- stage 1: stage 42x42 region of both images into LDS (zero-pad OOB) ----
    for (int idx = tid; idx < RR * RR; idx += BLK) {
        int r = idx / RR;
        int c = idx - r * RR;
        int gy = y0 + r, gx = x0 + c;
        float v1 = 0.f, v2 = 0.f;
        if ((unsigned)gy < (unsigned)IMG_H && (unsigned)gx < (unsigned)IMG_W) {
            int o = base + gy * IMG_W + gx;
            v1 = img1[o];
            v2 = img2[o];
        }
        s1[r][c] = v1;
        s2[r][c] = v2;
    }
    __syncthreads();

    // ---- stage 2: horizontal 11-tap pass for 5 quantities ----
    // work item = (row r in 0..41, 4-col segment); products formed on the fly
    for (int idx = tid; idx < RR * 8; idx += BLK) {
        int r  = idx >> 3;
        int c0 = (idx & 7) * 4;
        float a[16], b[16];
        #pragma unroll
        for (int ch = 0; ch < 4; ++ch) {
            *(float4*)&a[ch * 4] = *(const float4*)&s1[r][c0 + ch * 4];
            *(float4*)&b[ch * 4] = *(const float4*)&s2[r][c0 + ch * 4];
        }
        float hh[5][4];
        #pragma unroll
        for (int q = 0; q < 5; ++q)
            #pragma unroll
            for (int t = 0; t < 4; ++t) hh[q][t] = 0.f;
        #pragma unroll
        for (int k = 0; k < 11; ++k) {
            float w = gw[k];
            #pragma unroll
            for (int t = 0; t < 4; ++t) {
                float v1 = a[t + k], v2 = b[t + k];
                float t1 = w * v1, t2 = w * v2;
                hh[0][t] += t1;
                hh[1][t] += t2;
                hh[2][t] = fmaf(t1, v1, hh[2][t]);
                hh[3][t] = fmaf(t2, v2, hh[3][t]);
                hh[4][t] = fmaf(t1, v2, hh[4][t]);
            }
        }
        #pragma unroll
        for (int q = 0; q < 5; ++q)
            *(float4*)&hq[q][r][c0] = make_float4(hh[q][0], hh[q][1], hh[q][2], hh[q][3]);
    }
    __syncthreads();

    // ---- stage 3: vertical 11-tap pass + SSIM map; each thread owns a 2x2 patch ----
    const int ox = (tid & 15) * 2;
    const int oy = (tid >> 4) * 2;
    float va[5][2][2];
    #pragma unroll
    for (int q = 0; q < 5; ++q)
        #pragma unroll
        for (int t = 0; t < 2; ++t) { va[q][t][0] = 0.f; va[q][t][1] = 0.f; }

    #pragma unroll
    for (int rr = 0; rr < 12; ++rr) {
        int row = oy + rr;
        float w0 = (rr <= 10) ? gw[rr] : 0.f;       // tap for output row oy
        float w1 = (rr >= 1) ? gw[rr - 1] : 0.f;    // tap for output row oy+1
        #pragma unroll
        for (int q = 0; q < 5; ++q) {
            float2 hv = *(const float2*)&hq[q][row][ox];
            va[q][0][0] = fmaf(w0, hv.x, va[q][0][0]);
            va[q][0][1] = fmaf(w0, hv.y, va[q][0][1]);
            va[q][1][0] = fmaf(w1, hv.x, va[q][1][0]);
            va[q][1][1] = fmaf(w1, hv.y, va[q][1][1]);
        }
    }

    const float C1 = 1.0e-4f, C2 = 9.0e-4f, C3 = 4.5e-4f;
    float sL = 0.f, sC = 0.f, sS = 0.f;
    #pragma unroll
    for (int t = 0; t < 2; ++t) {
        #pragma unroll
        for (int c = 0; c < 2; ++c) {
            float mu1 = va[0][t][c], mu2 = va[1][t][c];
            float x11 = va[2][t][c], x22 = va[3][t][c], x12 = va[4][t][c];
            float mu1s = mu1 * mu1, mu2s = mu2 * mu2, mu12 = mu1 * mu2;
            float v1  = x11 - mu1s;
            float v2  = x22 - mu2s;
            float v12 = x12 - mu12;
            float a1 = fabsf(v1), a2 = fabsf(v2);
            float q1 = sqrtf(a1), q2 = sqrtf(a2);
            sL += __fdividef(2.f * mu12 + C1, mu1s + mu2s + C1);
            sC += __fdividef(2.f * q1 * q2 + C2, a1 + a2 + C2);
            sS += __fdividef(v12 + C3, q1 * q2 + C3);
        }
    }

    // ---- block reduction: wave shuffle (width 64) -> LDS -> 3 double atomics ----
    #pragma unroll
    for (int off = 32; off > 0; off >>= 1) {
        sL += __shfl_down(sL, off, 64);
        sC += __shfl_down(sC, off, 64);
        sS += __shfl_down(sS, off, 64);
    }
    int wave = tid >> 6;
    if ((tid & 63) == 0) { red[0][wave] = sL; red[1][wave] = sC; red[2][wave] = sS; }
    __syncthreads();
    if (tid == 0) {
        double tL = 0.0, tC = 0.0, tS = 0.0;
        #pragma unroll
        for (int w = 0; w < 4; ++w) { tL += red[0][w]; tC += red[1][w]; tS += red[2][w]; }
        atomicAdd(&acc[0], tL);
        atomicAdd(&acc[1], tC);
        atomicAdd(&acc[2], tS);
    }
}

__global__ void ssim_finalize(const double* __restrict__ acc, float* __restrict__ out) {
    int i = threadIdx.x;
    if (i < 3) out[i] = (float)(acc[i] * INV_NPIX);
}

extern "C" void kernel_launch(void* const* d_in, const int* in_sizes, int n_in,
                              void* d_out, int out_size, void* d_ws, size_t ws_size,
                              hipStream_t stream) {
    const float* img1 = (const float*)d_in[0];
    const float* img2 = (const float*)d_in[1];
    const float* win  = (const float*)d_in[2];
    float* out  = (float*)d_out;
    double* acc = (double*)d_ws;

    ssim_zero_acc<<<1, 64, 0, stream>>>(acc);
    dim3 grid(IMG_W / TILE, IMG_H / TILE, 96);   // 16 x 16 x (32 N * 3 C)
    ssim_tile_kernel<<<grid, BLK, 0, stream>>>(img1, img2, win, acc);
    ssim_finalize<<<1, 64, 0, stream>>>(acc, out);
}

// Round 2
// 330.709 us; speedup vs baseline: 3.2377x; 3.2377x over previous
//
#include <hip/hip_runtime.h>
#include <math.h>

#define IMG 512
#define PLANES 96            // 32 N * 3 C
#define XS_W 54              // valid output columns per wave (64 lanes - 10 halo)
#define NXS 10               // ceil(512/54)
#define YS_H 64              // output rows per wave
#define NYS 8                // 512/64
#define WPB 4                // waves per block
#define NSLOT 32
#define ACC_STRIDE 16        // doubles per atomic slot (128 B cacheline pad)
#define INV_NPIX (1.0 / 25165824.0)

// ws layout: [0, 4096) : double acc[NSLOT*ACC_STRIDE]; [4096, 4140) : float gw[11]

__global__ void ssim_init(double* __restrict__ acc, float* __restrict__ gwp,
                          const float* __restrict__ win) {
    int i = threadIdx.x;
    if (i < NSLOT * ACC_STRIDE) acc[i] = 0.0;
    // separable 1-D Gaussian from diagonal of 2-D window (channel 0): w2d[i][i]=g[i]^2
    if (i < 11) gwp[i] = sqrtf(win[i * 12]);
}

template<int P>
__device__ __forceinline__ void row_step(
    int T, int y0, bool col_ok,
    const float* __restrict__ p1, const float* __restrict__ p2,
    float& x1, float& x2, const int (&si)[11], const float* __restrict__ g,
    float (&A)[5][11], bool out_ok, float& sL, float& sC, float& sS)
{
    const int t = T + P;
    // ---- prefetch row t+1 (coalesced: lane = column) ----
    const int gy_next = y0 - 4 + t;
    float nx1 = 0.f, nx2 = 0.f;
    if (col_ok && (unsigned)gy_next < IMG) {
        int off = gy_next * IMG;
        nx1 = p1[off];
        nx2 = p2[off];
    }
    // ---- horizontal window via lane shifts (conflict-free bpermute) ----
    float a[11], b[11];
    #pragma unroll
    for (int j = 0; j < 11; ++j) {
        if (j == 5) { a[j] = x1; b[j] = x2; }
        else {
            a[j] = __int_as_float(__builtin_amdgcn_ds_bpermute(si[j], __float_as_int(x1)));
            b[j] = __int_as_float(__builtin_amdgcn_ds_bpermute(si[j], __float_as_int(x2)));
        }
    }
    // ---- horizontal 11-tap for 5 quantities (weights in SGPRs) ----
    float H1 = 0.f, H2 = 0.f, H11 = 0.f, H22 = 0.f, H12 = 0.f;
    #pragma unroll
    for (int j = 0; j < 11; ++j) {
        float w = g[j];
        float t1 = w * a[j], t2 = w * b[j];
        H1 += t1; H2 += t2;
        H11 = fmaf(t1, a[j], H11);
        H22 = fmaf(t2, b[j], H22);
        H12 = fmaf(t1, b[j], H12);
    }
    // ---- vertical accumulate into ring: H_t -> output r=t-10+j, weight g[10-j],
    //      slot (t+j+1)%11 ; statically indexed since t ≡ P (mod 11) ----
    #pragma unroll
    for (int j = 0; j < 11; ++j) {
        const int s = (P + j + 1) % 11;
        float w = g[10 - j];
        A[0][s] = fmaf(w, H1,  A[0][s]);
        A[1][s] = fmaf(w, H2,  A[1][s]);
        A[2][s] = fmaf(w, H11, A[2][s]);
        A[3][s] = fmaf(w, H22, A[3][s]);
        A[4][s] = fmaf(w, H12, A[4][s]);
    }
    // ---- emit output row r = t-10 (slot (P+1)%11), then recycle the slot ----
    const int es = (P + 1) % 11;
    if (t >= 10 && t <= 73) {                      // wave-uniform branch
        float mu1 = A[0][es], mu2 = A[1][es];
        float x11 = A[2][es], x22 = A[3][es], x12 = A[4][es];
        float mu1s = mu1 * mu1, mu2s = mu2 * mu2, mu12 = mu1 * mu2;
        float v1 = x11 - mu1s, v2 = x22 - mu2s, v12 = x12 - mu12;
        float a1 = fabsf(v1), a2 = fabsf(v2);
        float q12 = sqrtf(a1 * a2);                // sqrt(a1)*sqrt(a2)
        const float C1 = 1e-4f, C2 = 9e-4f, C3 = 4.5e-4f;
        float eL = __fdividef(2.f * mu12 + C1, mu1s + mu2s + C1);
        float eC = __fdividef(2.f * q12 + C2, a1 + a2 + C2);
        float eS = __fdividef(v12 + C3, q12 + C3);
        if (out_ok) { sL += eL; sC += eC; sS += eS; }
    }
    #pragma unroll
    for (int q = 0; q < 5; ++q) A[q][es] = 0.f;
    x1 = nx1; x2 = nx2;
}

__global__ __launch_bounds__(256, 4) void ssim_main(
    const float* __restrict__ img1, const float* __restrict__ img2,
    const float* __restrict__ gwp, double* __restrict__ acc)
{
    const int lane = threadIdx.x & 63;
    const int wid  = blockIdx.x * WPB + (threadIdx.x >> 6);
    const int plane = wid / (NXS * NYS);
    const int rem   = wid % (NXS * NYS);
    const int ys = rem / NXS, xs = rem % NXS;
    const int x0 = xs * XS_W;
    const int y0 = ys * YS_H;
    const int col = x0 - 5 + lane;                 // this lane's image column
    const bool col_ok = (unsigned)col < IMG;
    const bool out_ok = (lane >= 5) && (lane <= 58) && col_ok;

    // weights: thread-uniform loads -> SGPRs
    const float* g = gwp;

    // bpermute byte-indices for lane shifts -5..+5 (loop-invariant)
    int si[11];
    #pragma unroll
    for (int j = 0; j < 11; ++j) si[j] = (lane + j - 5) << 2;

    const float* p1 = img1 + (size_t)plane * (IMG * IMG) + col;
    const float* p2 = img2 + (size_t)plane * (IMG * IMG) + col;

    // load row t=0 (gy = y0-5)
    float x1 = 0.f, x2 = 0.f;
    {
        int gy = y0 - 5;
        if (col_ok && (unsigned)gy < IMG) { x1 = p1[gy * IMG]; x2 = p2[gy * IMG]; }
    }

    float A[5][11];
    #pragma unroll
    for (int q = 0; q < 5; ++q)
        #pragma unroll
        for (int s = 0; s < 11; ++s) A[q][s] = 0.f;

    float sL = 0.f, sC = 0.f, sS = 0.f;

    #pragma unroll 1
    for (int T = 0; T < 66; T += 11) {             // t = 0..65
        row_step<0>(T, y0, col_ok, p1, p2, x1, x2, si, g, A, out_ok, sL, sC, sS);
        row_step<1>(T, y0, col_ok, p1, p2, x1, x2, si, g, A, out_ok, sL, sC, sS);
        row_step<2>(T, y0, col_ok, p1, p2, x1, x2, si, g, A, out_ok, sL, sC, sS);
        row_step<3>(T, y0, col_ok, p1, p2, x1, x2, si, g, A, out_ok, sL, sC, sS);
        row_step<4>(T, y0, col_ok, p1, p2, x1, x2, si, g, A, out_ok, sL, sC, sS);
        row_step<5>(T, y0, col_ok, p1, p2, x1, x2, si, g, A, out_ok, sL, sC, sS);
        row_step<6>(T, y0, col_ok, p1, p2, x1, x2, si, g, A, out_ok, sL, sC, sS);
        row_step<7>(T, y0, col_ok, p1, p2, x1, x2, si, g, A, out_ok, sL, sC, sS);
        row_step<8>(T, y0, col_ok, p1, p2, x1, x2, si, g, A, out_ok, sL, sC, sS);
        row_step<9>(T, y0, col_ok, p1, p2, x1, x2, si, g, A, out_ok, sL, sC, sS);
        row_step<10>(T, y0, col_ok, p1, p2, x1, x2, si, g, A, out_ok, sL, sC, sS);
    }
    // tail: t = 66..73
    row_step<0>(66, y0, col_ok, p1, p2, x1, x2, si, g, A, out_ok, sL, sC, sS);
    row_step<1>(66, y0, col_ok, p1, p2, x1, x2, si, g, A, out_ok, sL, sC, sS);
    row_step<2>(66, y0, col_ok, p1, p2, x1, x2, si, g, A, out_ok, sL, sC, sS);
    row_step<3>(66, y0, col_ok, p1, p2, x1, x2, si, g, A, out_ok, sL, sC, sS);
    row_step<4>(66, y0, col_ok, p1, p2, x1, x2, si, g, A, out_ok, sL, sC, sS);
    row_step<5>(66, y0, col_ok, p1, p2, x1, x2, si, g, A, out_ok, sL, sC, sS);
    row_step<6>(66, y0, col_ok, p1, p2, x1, x2, si, g, A, out_ok, sL, sC, sS);
    row_step<7>(66, y0, col_ok, p1, p2, x1, x2, si, g, A, out_ok, sL, sC, sS);

    // ---- wave reduction (no barriers), then one diluted atomic set per wave ----
    #pragma unroll
    for (int off = 32; off > 0; off >>= 1) {
        sL += __shfl_down(sL, off, 64);
        sC += __shfl_down(sC, off, 64);
        sS += __shfl_down(sS, off, 64);
    }
    if (lane == 0) {
        double* slot = acc + (size_t)(wid & (NSLOT - 1)) * ACC_STRIDE;
        atomicAdd(slot + 0, (double)sL);
        atomicAdd(slot + 1, (double)sC);
        atomicAdd(slot + 2, (double)sS);
    }
}

__global__ void ssim_fin(const double* __restrict__ acc, float* __restrict__ out) {
    int i = threadIdx.x;
    if (i < 3) {
        double s = 0.0;
        for (int k = 0; k < NSLOT; ++k) s += acc[k * ACC_STRIDE + i];
        out[i] = (float)(s * INV_NPIX);
    }
}

extern "C" void kernel_launch(void* const* d_in, const int* in_sizes, int n_in,
                              void* d_out, int out_size, void* d_ws, size_t ws_size,
                              hipStream_t stream) {
    const float* img1 = (const float*)d_in[0];
    const float* img2 = (const float*)d_in[1];
    const float* win  = (const float*)d_in[2];
    float* out = (float*)d_out;
    double* acc = (double*)d_ws;
    float* gwp = (float*)((char*)d_ws + NSLOT * ACC_STRIDE * sizeof(double));

    ssim_init<<<1, 512, 0, stream>>>(acc, gwp, win);
    ssim_main<<<(PLANES * NXS * NYS) / WPB, 64 * WPB, 0, stream>>>(img1, img2, gwp, acc);
    ssim_fin<<<1, 64, 0, stream>>>(acc, out);
}